// Round 4
// baseline (1134.672 us; speedup 1.0000x reference)
//
#include <hip/hip_runtime.h>
#include <hip/hip_bf16.h>

// Fused linear + SimPO loss for B=8,T=512,H=2048,V=32000 (fp32 in, scalar out).
// Plan: (1) convert W,input to bf16 in ws; (2) m97-structure bf16 MFMA GEMM with
// global_load_lds(16B) emitting per-(row, 64-col-half) online-softmax partials
// (never materializes 4096x32000 logits); (3) exact fp32 target-logit dot;
// (4) small merge + loss kernels. Fallback (small ws): fp32-reg-staged GEMM.

constexpr int Bb = 8, Tt = 512, Hh = 2048, Vv = 32000;
constexpr int Mrows = Bb * Tt;     // 4096
constexpr int K4 = Hh / 4;         // 512 float4 per row
constexpr int BM = 128, BN = 128, BK = 64;
constexpr int NRT = Mrows / BM;    // 32
constexpr int NVT = Vv / BN;       // 250
constexpr int NVT2 = NVT * 2;      // 500 partial slots/row (one per 64-col half)
constexpr int NKS = Hh / BK;       // 32
constexpr int LDK = BK + 8;        // fallback-path pad

typedef __attribute__((ext_vector_type(8))) short short8;
typedef __attribute__((ext_vector_type(4))) float f32x4;
typedef unsigned short ushort_t;

// Manual RNE fp32->bf16 pack (bit-exact vs v_cvt_pk_bf16_f32 for non-NaN).
__device__ __forceinline__ unsigned pkbf2(float x, float y) {
  const unsigned ux = __builtin_bit_cast(unsigned, x);
  const unsigned uy = __builtin_bit_cast(unsigned, y);
  const unsigned rx = (ux + 0x7fffu + ((ux >> 16) & 1u)) >> 16;
  const unsigned ry = (uy + 0x7fffu + ((uy >> 16) & 1u)) >> 16;
  return (rx & 0xffffu) | (ry << 16);
}

__device__ __forceinline__ void gload16(const void* g, void* l) {
  __builtin_amdgcn_global_load_lds(
      (const __attribute__((address_space(1))) unsigned*)g,
      (__attribute__((address_space(3))) unsigned*)l, 16, 0, 0);
}

// ---------------- kernel 0: fp32 -> bf16 bulk convert (vectorized)
__global__ __launch_bounds__(256) void cvt_kernel(
    const float* __restrict__ src, unsigned* __restrict__ dst, int n4)
{
  const int stride = gridDim.x * 256;
  for (int i = blockIdx.x * 256 + threadIdx.x; i < n4; i += stride) {
    const float4 v = ((const float4*)src)[i];
    uint2 o;
    o.x = pkbf2(v.x, v.y);
    o.y = pkbf2(v.z, v.w);
    ((uint2*)dst)[i] = o;
  }
}

// Shared epilogue: per-row (max, sum-exp) over this wave's 64-col half.
// C/D layout (m89/m91): col = lane&15, row = (lane>>4)*4 + reg.
__device__ __forceinline__ void lse_epilogue(
    f32x4 (&acc)[4][4], const float* __restrict__ bias,
    float* __restrict__ pmax, float* __restrict__ psum,
    int rt, int vt, int wr, int wc, int lane)
{
  const int lane15 = lane & 15, q = lane >> 4;
  const int pcol = vt * 2 + (wc >> 6);   // unique per (row-half, col-half) wave
  float bj[4];
#pragma unroll
  for (int j = 0; j < 4; ++j) bj[j] = bias[vt * BN + wc + j * 16 + lane15];
#pragma unroll
  for (int i = 0; i < 4; ++i) {
#pragma unroll
    for (int r = 0; r < 4; ++r) {
      const float v0 = acc[i][0][r] + bj[0];
      const float v1 = acc[i][1][r] + bj[1];
      const float v2 = acc[i][2][r] + bj[2];
      const float v3 = acc[i][3][r] + bj[3];
      float mx = fmaxf(fmaxf(v0, v1), fmaxf(v2, v3));
#pragma unroll
      for (int m = 1; m < 16; m <<= 1) mx = fmaxf(mx, __shfl_xor(mx, m));
      float sm = __expf(v0 - mx) + __expf(v1 - mx) + __expf(v2 - mx) + __expf(v3 - mx);
#pragma unroll
      for (int m = 1; m < 16; m <<= 1) sm += __shfl_xor(sm, m);
      if (lane15 == 0) {
        const int grow = rt * BM + wr + i * 16 + q * 4 + r;
        pmax[(size_t)grow * NVT2 + pcol] = mx;
        psum[(size_t)grow * NVT2 + pcol] = sm;
      }
    }
  }
}

// ---------------- kernel 1 (main): bf16 GEMM, m97 structure -> lse partials
__global__ __launch_bounds__(256) void gemm_bf16(
    const ushort_t* __restrict__ Wb, const ushort_t* __restrict__ inpb,
    const float* __restrict__ bias,
    float* __restrict__ pmax, float* __restrict__ psum)
{
  __shared__ ushort_t At[BM][BK];   // linear: global_load_lds needs no padding
  __shared__ ushort_t Bt[BN][BK];

  const int tid = threadIdx.x;
  // XCD-bijective swizzle (8000 = 8*1000): each XCD owns a vocab band ->
  // its W slice is read ~once from HBM; input (16.8 MB bf16) stays L3-resident.
  const int o  = (blockIdx.x & 7) * (NRT * NVT / 8) + (blockIdx.x >> 3);
  const int vt = o >> 5;   // o / NRT
  const int rt = o & 31;   // o % NRT

  const int lane = tid & 63;
  const int wv = tid >> 6;
  const int wr = (wv >> 1) * 64;
  const int wc = (wv & 1) * 64;

  // staging: wave wv owns rows [32*wv, 32*wv+32), 4 chunks of 8 rows;
  // lane l covers row (l>>3), 16B at col (l&7)*8 within a chunk.
  const ushort_t* gA = inpb + (size_t)(rt * BM + wv * 32 + (lane >> 3)) * Hh + (lane & 7) * 8;
  const ushort_t* gB = Wb   + (size_t)(vt * BN + wv * 32 + (lane >> 3)) * Hh + (lane & 7) * 8;
  ushort_t* lA = &At[0][0] + wv * 2048 + lane * 8;  // wave base + lane*16B
  ushort_t* lB = &Bt[0][0] + wv * 2048 + lane * 8;

  f32x4 acc[4][4];
#pragma unroll
  for (int i = 0; i < 4; ++i)
#pragma unroll
    for (int j = 0; j < 4; ++j) acc[i][j] = {0.f, 0.f, 0.f, 0.f};

  for (int ks = 0; ks < NKS; ++ks) {
#pragma unroll
    for (int c = 0; c < 4; ++c) {            // 8x global_load_lds_dwordx4
      gload16(gA + (size_t)c * 8 * Hh + ks * BK, lA + c * 512);
      gload16(gB + (size_t)c * 8 * Hh + ks * BK, lB + c * 512);
    }
    __syncthreads();                         // drains vmcnt -> tiles staged
#pragma unroll
    for (int kk = 0; kk < 2; ++kk) {
      const int kb = kk * 32 + (lane >> 4) * 8;
      const int rr = lane & 15;
      short8 a[4], b[4];
#pragma unroll
      for (int i = 0; i < 4; ++i) a[i] = *(const short8*)&At[wr + i * 16 + rr][kb];
#pragma unroll
      for (int j = 0; j < 4; ++j) b[j] = *(const short8*)&Bt[wc + j * 16 + rr][kb];
#pragma unroll
      for (int i = 0; i < 4; ++i)
#pragma unroll
        for (int j = 0; j < 4; ++j)
          acc[i][j] = __builtin_amdgcn_mfma_f32_16x16x32_bf16(a[i], b[j], acc[i][j], 0, 0, 0);
    }
    __syncthreads();                         // done reading before next overwrite
  }

  lse_epilogue(acc, bias, pmax, psum, rt, vt, wr, wc, lane);
}

// ---------------- fallback GEMM (fp32 inputs reg-staged, padded LDS)
__global__ __launch_bounds__(256) void gemm_partials(
    const float* __restrict__ W, const float* __restrict__ inp,
    const float* __restrict__ bias,
    float* __restrict__ pmax, float* __restrict__ psum)
{
  __shared__ ushort_t At[BM][LDK];
  __shared__ ushort_t Bt[BN][LDK];

  const int tid = threadIdx.x;
  const int o  = (blockIdx.x & 7) * (NRT * NVT / 8) + (blockIdx.x >> 3);
  const int vt = o >> 5;
  const int rt = o & 31;

  const int lane = tid & 63;
  const int wv = tid >> 6;
  const int wr = (wv >> 1) * 64;
  const int wc = (wv & 1) * 64;
  const int r0 = tid >> 4;
  const int c4 = tid & 15;

  const float4* Ag = (const float4*)inp + (size_t)(rt * BM) * K4;
  const float4* Bg = (const float4*)W  + (size_t)(vt * BN) * K4;

  float4 ar[8], br[8];
  auto issue = [&](int ks) {
    const int kb = ks * (BK / 4);
#pragma unroll
    for (int it = 0; it < 8; ++it) {
      ar[it] = Ag[(size_t)(r0 + it * 16) * K4 + kb + c4];
      br[it] = Bg[(size_t)(r0 + it * 16) * K4 + kb + c4];
    }
  };

  f32x4 acc[4][4];
#pragma unroll
  for (int i = 0; i < 4; ++i)
#pragma unroll
    for (int j = 0; j < 4; ++j) acc[i][j] = {0.f, 0.f, 0.f, 0.f};

  issue(0);
  for (int ks = 0; ks < NKS; ++ks) {
    __syncthreads();
#pragma unroll
    for (int it = 0; it < 8; ++it) {
      uint2 ua, ub;
      ua.x = pkbf2(ar[it].x, ar[it].y); ua.y = pkbf2(ar[it].z, ar[it].w);
      ub.x = pkbf2(br[it].x, br[it].y); ub.y = pkbf2(br[it].z, br[it].w);
      *(uint2*)&At[r0 + it * 16][c4 * 4] = ua;
      *(uint2*)&Bt[r0 + it * 16][c4 * 4] = ub;
    }
    __syncthreads();
    if (ks + 1 < NKS) issue(ks + 1);
#pragma unroll
    for (int kk = 0; kk < 2; ++kk) {
      const int kb = kk * 32 + (lane >> 4) * 8;
      const int rr = lane & 15;
      short8 a[4], b[4];
#pragma unroll
      for (int i = 0; i < 4; ++i) a[i] = *(const short8*)&At[wr + i * 16 + rr][kb];
#pragma unroll
      for (int j = 0; j < 4; ++j) b[j] = *(const short8*)&Bt[wc + j * 16 + rr][kb];
#pragma unroll
      for (int i = 0; i < 4; ++i)
#pragma unroll
        for (int j = 0; j < 4; ++j)
          acc[i][j] = __builtin_amdgcn_mfma_f32_16x16x32_bf16(a[i], b[j], acc[i][j], 0, 0, 0);
    }
  }

  lse_epilogue(acc, bias, pmax, psum, rt, vt, wr, wc, lane);
}

// ---------------- kernel 2: exact fp32 target logits
__global__ __launch_bounds__(256) void tgt_kernel(
    const float* __restrict__ inp, const float* __restrict__ W,
    const int* __restrict__ target, const float* __restrict__ bias,
    float* __restrict__ tl)
{
  const int row = blockIdx.x;
  int tgt = target[row];
  const int tgtc = tgt < 0 ? 0 : tgt;
  const float4* a = (const float4*)inp + (size_t)row * K4;
  const float4* w = (const float4*)W + (size_t)tgtc * K4;
  const int t = threadIdx.x;
  float s = 0.f;
  for (int i = t; i < K4; i += 256) {
    const float4 x = a[i], y = w[i];
    s += x.x * y.x + x.y * y.y + x.z * y.z + x.w * y.w;
  }
#pragma unroll
  for (int m = 1; m < 64; m <<= 1) s += __shfl_xor(s, m);
  __shared__ float red[4];
  if ((t & 63) == 0) red[t >> 6] = s;
  __syncthreads();
  if (t == 0) tl[row] = red[0] + red[1] + red[2] + red[3] + bias[tgtc];
}

// ---------------- kernel 3: merge partials -> tok_logp per row
__global__ __launch_bounds__(64) void lse_kernel(
    const float* __restrict__ pmax, const float* __restrict__ psum,
    const float* __restrict__ tl, float* __restrict__ tok)
{
  const int row = blockIdx.x;
  const int l = threadIdx.x;
  const float* pm = pmax + (size_t)row * NVT2;
  const float* ps = psum + (size_t)row * NVT2;
  float M = -3.4e38f;
  for (int t = l; t < NVT2; t += 64) M = fmaxf(M, pm[t]);
#pragma unroll
  for (int m = 1; m < 64; m <<= 1) M = fmaxf(M, __shfl_xor(M, m));
  float S = 0.f;
  for (int t = l; t < NVT2; t += 64) S += ps[t] * __expf(pm[t] - M);
#pragma unroll
  for (int m = 1; m < 64; m <<= 1) S += __shfl_xor(S, m);
  if (l == 0) tok[row] = tl[row] - (M + logf(S));
}

// ---------------- kernel 4: SimPO loss scalar
__global__ __launch_bounds__(512) void final_kernel(
    const float* __restrict__ tok, const int* __restrict__ target,
    float* __restrict__ out)
{
  const int w = threadIdx.x >> 6;
  const int l = threadIdx.x & 63;
  float s = 0.f, c = 0.f;
  for (int i = l; i < Tt; i += 64) {
    const int row = w * Tt + i;
    const bool msk = target[row] != -100;
    s += msk ? tok[row] : 0.f;
    c += msk ? 1.f : 0.f;
  }
#pragma unroll
  for (int m = 1; m < 64; m <<= 1) { s += __shfl_xor(s, m); c += __shfl_xor(c, m); }
  __shared__ float sums[8], cnts[8];
  if (l == 0) { sums[w] = s; cnts[w] = c; }
  __syncthreads();
  if (threadIdx.x == 0) {
    float avg[8];
    float nsum = 0.f, ncnt = 0.f;
    for (int b = 0; b < 8; ++b) {
      avg[b] = sums[b] / cnts[b];
      if (b < 4) { nsum += sums[b]; ncnt += cnts[b]; }
    }
    const float nll = -nsum / ncnt;
    float pref = 0.f;
    for (int i = 0; i < 4; ++i) {
      const float z = 0.1f * (avg[i] - avg[i + 4]) - 0.5f;
      const float ls = fminf(z, 0.f) - log1pf(__expf(-fabsf(z)));
      pref += -ls;                 // LABEL_SMOOTHING = 0
    }
    pref *= 0.25f;
    out[0] = 1.0f * nll + pref;    // ALPHA = 1
  }
}

extern "C" void kernel_launch(void* const* d_in, const int* in_sizes, int n_in,
                              void* d_out, int out_size, void* d_ws, size_t ws_size,
                              hipStream_t stream) {
  const float* W    = (const float*)d_in[0];
  const float* inp  = (const float*)d_in[1];
  const int*   tgt  = (const int*)d_in[2];
  const float* bias = (const float*)d_in[3];
  char* ws = (char*)d_ws;

  constexpr size_t szWb   = (size_t)Vv * Hh * 2;       // 131,072,000
  constexpr size_t szInb  = (size_t)Mrows * Hh * 2;    //  16,777,216
  constexpr size_t szPart = (size_t)Mrows * NVT2 * 4;  //   8,192,000
  constexpr size_t need   = szWb + szInb + 2 * szPart + 2 * (size_t)Mrows * 4;

  if (ws_size >= need) {
    ushort_t* Wb   = (ushort_t*)ws;
    ushort_t* inpb = (ushort_t*)(ws + szWb);
    float* pmax = (float*)(ws + szWb + szInb);
    float* psum = (float*)(ws + szWb + szInb + szPart);
    float* tl   = (float*)(ws + szWb + szInb + 2 * szPart);
    float* tok  = (float*)(ws + szWb + szInb + 2 * szPart + (size_t)Mrows * 4);

    hipLaunchKernelGGL(cvt_kernel, dim3(2048), dim3(256), 0, stream,
                       W, (unsigned*)Wb, Vv * Hh / 4);
    hipLaunchKernelGGL(cvt_kernel, dim3(2048), dim3(256), 0, stream,
                       inp, (unsigned*)inpb, Mrows * Hh / 4);
    hipLaunchKernelGGL(gemm_bf16, dim3(NRT * NVT), dim3(256), 0, stream,
                       Wb, inpb, bias, pmax, psum);
    hipLaunchKernelGGL(tgt_kernel, dim3(Mrows), dim3(256), 0, stream,
                       inp, W, tgt, bias, tl);
    hipLaunchKernelGGL(lse_kernel, dim3(Mrows), dim3(64), 0, stream,
                       pmax, psum, tl, tok);
    hipLaunchKernelGGL(final_kernel, dim3(1), dim3(512), 0, stream,
                       tok, tgt, (float*)d_out);
  } else {
    float* pmax = (float*)ws;
    float* psum = (float*)(ws + szPart);
    float* tl   = (float*)(ws + 2 * szPart);
    float* tok  = (float*)(ws + 2 * szPart + (size_t)Mrows * 4);

    hipLaunchKernelGGL(gemm_partials, dim3(NRT * NVT), dim3(256), 0, stream,
                       W, inp, bias, pmax, psum);
    hipLaunchKernelGGL(tgt_kernel, dim3(Mrows), dim3(256), 0, stream,
                       inp, W, tgt, bias, tl);
    hipLaunchKernelGGL(lse_kernel, dim3(Mrows), dim3(64), 0, stream,
                       pmax, psum, tl, tok);
    hipLaunchKernelGGL(final_kernel, dim3(1), dim3(512), 0, stream,
                       tok, tgt, (float*)d_out);
  }
}

// Round 5
// 922.876 us; speedup vs baseline: 1.2295x; 1.2295x over previous
//
#include <hip/hip_runtime.h>
#include <hip/hip_bf16.h>

// Fused linear + SimPO loss for B=8,T=512,H=2048,V=32000 (fp32 in, scalar out).
// R5: 256x256-tile 8-wave deep-pipelined bf16 MFMA GEMM (T2 swizzle + T3/T4
// counted-vmcnt phase schedule + T5 setprio), online-softmax partials fused in
// epilogue. Pre-converts W/input to bf16 in ws. Exact fp32 target-logit dot.

constexpr int Bb = 8, Tt = 512, Hh = 2048, Vv = 32000;
constexpr int Mrows = Bb * Tt;     // 4096
constexpr int K4 = Hh / 4;         // 512 float4 per row
constexpr int NVT2 = Vv / 64;      // 500 partial slots/row (one per 64-col band)
constexpr int NT64 = Hh / 64;      // 32 K-tiles of 64
// fallback-path tile params
constexpr int BMf = 128, BNf = 128, LDK = 64 + 8;
constexpr int NRTf = Mrows / BMf, NVTf = Vv / BNf, NKSf = Hh / 64;

typedef __attribute__((ext_vector_type(8))) short short8;
typedef __attribute__((ext_vector_type(4))) float f32x4;
typedef unsigned short ushort_t;

// Manual RNE fp32->bf16 pack (bit-exact vs v_cvt_pk_bf16_f32 for non-NaN).
__device__ __forceinline__ unsigned pkbf2(float x, float y) {
  const unsigned ux = __builtin_bit_cast(unsigned, x);
  const unsigned uy = __builtin_bit_cast(unsigned, y);
  const unsigned rx = (ux + 0x7fffu + ((ux >> 16) & 1u)) >> 16;
  const unsigned ry = (uy + 0x7fffu + ((uy >> 16) & 1u)) >> 16;
  return (rx & 0xffffu) | (ry << 16);
}

__device__ __forceinline__ void gload16(const void* g, void* l) {
  __builtin_amdgcn_global_load_lds(
      (const __attribute__((address_space(1))) unsigned*)g,
      (__attribute__((address_space(3))) unsigned*)l, 16, 0, 0);
}

// ---------------- kernel 0: fp32 -> bf16 bulk convert (vectorized)
__global__ __launch_bounds__(256) void cvt_kernel(
    const float* __restrict__ src, unsigned* __restrict__ dst, int n4)
{
  const int stride = gridDim.x * 256;
  for (int i = blockIdx.x * 256 + threadIdx.x; i < n4; i += stride) {
    const float4 v = ((const float4*)src)[i];
    uint2 o;
    o.x = pkbf2(v.x, v.y);
    o.y = pkbf2(v.z, v.w);
    ((uint2*)dst)[i] = o;
  }
}

// ---------------- kernel 1 (main): 256^2 8-wave pipelined bf16 GEMM ->
//                  per-(row, 64-col-band) online-softmax partials.
// Geometry: BM=BN=256, BK=64, 8 waves (2M x 4N), per-wave 128x64 output,
// acc[8][4] f32x4. LDS: 8 regions x 16KB = 128KB:
//   region = buf(2) * 4 + {A_half0, A_half1, B_half0, B_half1}, each [128][64] bf16.
// Swizzle: data for logical (row, chunk c) stored at chunk c^(row&7) (16B chunks).
//   Stager (linear global_load_lds dest) pre-swizzles the SOURCE chunk;
//   readers XOR their chunk with (row&7). (rule #21: both sides.)
// Pipeline: half-tiles (2 loads/thread) staged 6 ahead; 1 staged per phase;
//   4 phases per K-tile; boundary s_waitcnt vmcnt(4) (counted, 0 only entering
//   the last tile); raw s_barrier (no implicit drain); setprio around MFMA.
// Region-overwrite safety: A-half reads confined to phases 0-1 (sealed by the
//   phase-1 closing barrier, one barrier before their overwriting load issues
//   at phases 2/3); B-half overwrites always target the idle buffer.
__global__ __launch_bounds__(512, 2) void gemm256(
    const ushort_t* __restrict__ Wb, const ushort_t* __restrict__ inpb,
    const float* __restrict__ bias,
    float* __restrict__ pmax, float* __restrict__ psum)
{
  extern __shared__ ushort_t lds[];   // 8 * 8192 ushorts = 128 KB

  const int tid = threadIdx.x;
  const int l  = tid & 63;
  const int wv = tid >> 6;          // wave 0..7
  const int wm = wv >> 2;           // M half 0..1
  const int wn = wv & 3;            // N quarter 0..3

  // XCD-bijective swizzle (2000 = 8*250): vocab-banded per XCD.
  const int o  = ((int)blockIdx.x & 7) * 250 + ((int)blockIdx.x >> 3);
  const int bn = o >> 4;            // 0..124
  const int bm = o & 15;            // 0..15
  const int rowA0 = bm * 256, rowB0 = bn * 256;

  // staging lane constants
  const int segr = l >> 3;                 // 0..7 row within 8-row segment
  const int csrc = (l & 7) ^ segr;         // pre-swizzled source chunk
  // reader lane constants
  const int arow = l & 15;
  const int kcb  = l >> 4;                 // 0..3 k-chunk base
  const int sx   = l & 7;                  // reader swizzle xor

  auto stage = [&](int H) {
    if (H >= 4 * NT64) return;
    const int T = H >> 2, m = H & 3;
    const ushort_t* src = (m < 2) ? inpb : Wb;
    const int r0 = ((m < 2) ? rowA0 : rowB0) + (m & 1) * 128;
    ushort_t* reg = lds + ((((T & 1) << 2) | m) << 13);
    const int kc = T * 64 + csrc * 8;
#pragma unroll
    for (int s = 0; s < 2; ++s) {
      const int seg = s * 8 + wv;
      gload16(src + (size_t)(r0 + seg * 8 + segr) * Hh + kc,
              reg + seg * 512 + l * 8);
    }
  };

  f32x4 acc[8][4];
#pragma unroll
  for (int i = 0; i < 8; ++i)
#pragma unroll
    for (int j = 0; j < 4; ++j) acc[i][j] = {0.f, 0.f, 0.f, 0.f};

  // prologue: 6 half-tiles (tile0 complete + tile1 A halves), wait tile0.
#pragma unroll
  for (int h = 0; h < 6; ++h) stage(h);
  asm volatile("s_waitcnt vmcnt(4)" ::: "memory");
  __builtin_amdgcn_s_barrier();

  const int browbase = (wn & 1) * 64;
  for (int t = 0; t < NT64; ++t) {
    const int bA = ((((t & 1) << 2) | wm) << 13);
    const int bB = ((((t & 1) << 2) | (2 + (wn >> 1))) << 13);
    short8 a0[8], a1[8], b0[4], b1[4];

    // ---- phase 0: read A kk0 + B kk0; stage t+1 B0; MFMA kk0 x j{0,1}
#pragma unroll
    for (int i = 0; i < 8; ++i)
      a0[i] = *(const short8*)(lds + bA + (i * 16 + arow) * 64 + ((kcb ^ sx) * 8));
#pragma unroll
    for (int j = 0; j < 4; ++j)
      b0[j] = *(const short8*)(lds + bB + (browbase + j * 16 + arow) * 64 + ((kcb ^ sx) * 8));
    stage(4 * t + 6);
    __builtin_amdgcn_s_barrier();
    __builtin_amdgcn_s_setprio(1);
#pragma unroll
    for (int i = 0; i < 8; ++i)
#pragma unroll
      for (int j = 0; j < 2; ++j)
        acc[i][j] = __builtin_amdgcn_mfma_f32_16x16x32_bf16(a0[i], b0[j], acc[i][j], 0, 0, 0);
    __builtin_amdgcn_s_setprio(0);
    __builtin_amdgcn_s_barrier();

    // ---- phase 1: read A kk1 + B kk1; stage t+1 B1; MFMA kk0 x j{2,3}
#pragma unroll
    for (int i = 0; i < 8; ++i)
      a1[i] = *(const short8*)(lds + bA + (i * 16 + arow) * 64 + (((4 + kcb) ^ sx) * 8));
#pragma unroll
    for (int j = 0; j < 4; ++j)
      b1[j] = *(const short8*)(lds + bB + (browbase + j * 16 + arow) * 64 + (((4 + kcb) ^ sx) * 8));
    stage(4 * t + 7);
    __builtin_amdgcn_s_barrier();
    __builtin_amdgcn_s_setprio(1);
#pragma unroll
    for (int i = 0; i < 8; ++i)
#pragma unroll
      for (int j = 2; j < 4; ++j)
        acc[i][j] = __builtin_amdgcn_mfma_f32_16x16x32_bf16(a0[i], b0[j], acc[i][j], 0, 0, 0);
    __builtin_amdgcn_s_setprio(0);
    __builtin_amdgcn_s_barrier();

    // ---- phase 2: stage t+2 A0; MFMA kk1 x j{0,1}
    stage(4 * t + 8);
    __builtin_amdgcn_s_barrier();
    __builtin_amdgcn_s_setprio(1);
#pragma unroll
    for (int i = 0; i < 8; ++i)
#pragma unroll
      for (int j = 0; j < 2; ++j)
        acc[i][j] = __builtin_amdgcn_mfma_f32_16x16x32_bf16(a1[i], b1[j], acc[i][j], 0, 0, 0);
    __builtin_amdgcn_s_setprio(0);
    __builtin_amdgcn_s_barrier();

    // ---- phase 3: stage t+2 A1; MFMA kk1 x j{2,3}; boundary vmcnt
    stage(4 * t + 9);
    __builtin_amdgcn_s_barrier();
    __builtin_amdgcn_s_setprio(1);
#pragma unroll
    for (int i = 0; i < 8; ++i)
#pragma unroll
      for (int j = 2; j < 4; ++j)
        acc[i][j] = __builtin_amdgcn_mfma_f32_16x16x32_bf16(a1[i], b1[j], acc[i][j], 0, 0, 0);
    __builtin_amdgcn_s_setprio(0);
    if (t < NT64 - 2)      asm volatile("s_waitcnt vmcnt(4)" ::: "memory");
    else if (t == NT64 - 2) asm volatile("s_waitcnt vmcnt(0)" ::: "memory");
    __builtin_amdgcn_s_barrier();
  }

  // epilogue: bias + per-row (max, sum-exp) over this wave's 64-col band.
  // C/D layout (m89/m91): col = lane&15, row = (lane>>4)*4 + reg.
  const int q = l >> 4;
  const int pcol = bn * 4 + wn;
  float bj[4];
#pragma unroll
  for (int j = 0; j < 4; ++j) bj[j] = bias[bn * 256 + wn * 64 + j * 16 + arow];
#pragma unroll
  for (int i = 0; i < 8; ++i) {
#pragma unroll
    for (int r = 0; r < 4; ++r) {
      const float v0 = acc[i][0][r] + bj[0];
      const float v1 = acc[i][1][r] + bj[1];
      const float v2 = acc[i][2][r] + bj[2];
      const float v3 = acc[i][3][r] + bj[3];
      float mx = fmaxf(fmaxf(v0, v1), fmaxf(v2, v3));
#pragma unroll
      for (int m = 1; m < 16; m <<= 1) mx = fmaxf(mx, __shfl_xor(mx, m));
      float sm = __expf(v0 - mx) + __expf(v1 - mx) + __expf(v2 - mx) + __expf(v3 - mx);
#pragma unroll
      for (int m = 1; m < 16; m <<= 1) sm += __shfl_xor(sm, m);
      if (arow == 0) {
        const int grow = bm * 256 + wm * 128 + i * 16 + q * 4 + r;
        pmax[(size_t)grow * NVT2 + pcol] = mx;
        psum[(size_t)grow * NVT2 + pcol] = sm;
      }
    }
  }
}

// ---------------- fallback GEMM (fp32 inputs reg-staged, padded LDS)
__global__ __launch_bounds__(256) void gemm_partials(
    const float* __restrict__ W, const float* __restrict__ inp,
    const float* __restrict__ bias,
    float* __restrict__ pmax, float* __restrict__ psum)
{
  __shared__ ushort_t At[BMf][LDK];
  __shared__ ushort_t Bt[BNf][LDK];

  const int tid = threadIdx.x;
  const int o  = (blockIdx.x & 7) * (NRTf * NVTf / 8) + (blockIdx.x >> 3);
  const int vt = o >> 5;
  const int rt = o & 31;

  const int lane = tid & 63;
  const int wv = tid >> 6;
  const int wr = (wv >> 1) * 64;
  const int wc = (wv & 1) * 64;
  const int r0 = tid >> 4;
  const int c4 = tid & 15;

  const float4* Ag = (const float4*)inp + (size_t)(rt * BMf) * K4;
  const float4* Bg = (const float4*)W  + (size_t)(vt * BNf) * K4;

  float4 ar[8], br[8];
  auto issue = [&](int ks) {
    const int kb = ks * 16;
#pragma unroll
    for (int it = 0; it < 8; ++it) {
      ar[it] = Ag[(size_t)(r0 + it * 16) * K4 + kb + c4];
      br[it] = Bg[(size_t)(r0 + it * 16) * K4 + kb + c4];
    }
  };

  f32x4 acc[4][4];
#pragma unroll
  for (int i = 0; i < 4; ++i)
#pragma unroll
    for (int j = 0; j < 4; ++j) acc[i][j] = {0.f, 0.f, 0.f, 0.f};

  issue(0);
  for (int ks = 0; ks < NKSf; ++ks) {
    __syncthreads();
#pragma unroll
    for (int it = 0; it < 8; ++it) {
      uint2 ua, ub;
      ua.x = pkbf2(ar[it].x, ar[it].y); ua.y = pkbf2(ar[it].z, ar[it].w);
      ub.x = pkbf2(br[it].x, br[it].y); ub.y = pkbf2(br[it].z, br[it].w);
      *(uint2*)&At[r0 + it * 16][c4 * 4] = ua;
      *(uint2*)&Bt[r0 + it * 16][c4 * 4] = ub;
    }
    __syncthreads();
    if (ks + 1 < NKSf) issue(ks + 1);
#pragma unroll
    for (int kk = 0; kk < 2; ++kk) {
      const int kb = kk * 32 + (lane >> 4) * 8;
      const int rr = lane & 15;
      short8 a[4], b[4];
#pragma unroll
      for (int i = 0; i < 4; ++i) a[i] = *(const short8*)&At[wr + i * 16 + rr][kb];
#pragma unroll
      for (int j = 0; j < 4; ++j) b[j] = *(const short8*)&Bt[wc + j * 16 + rr][kb];
#pragma unroll
      for (int i = 0; i < 4; ++i)
#pragma unroll
        for (int j = 0; j < 4; ++j)
          acc[i][j] = __builtin_amdgcn_mfma_f32_16x16x32_bf16(a[i], b[j], acc[i][j], 0, 0, 0);
    }
  }

  const int lane15 = lane & 15, q = lane >> 4;
  const int pcol = vt * 2 + (wc >> 6);
  float bj[4];
#pragma unroll
  for (int j = 0; j < 4; ++j) bj[j] = bias[vt * BNf + wc + j * 16 + lane15];
#pragma unroll
  for (int i = 0; i < 4; ++i) {
#pragma unroll
    for (int r = 0; r < 4; ++r) {
      const float v0 = acc[i][0][r] + bj[0];
      const float v1 = acc[i][1][r] + bj[1];
      const float v2 = acc[i][2][r] + bj[2];
      const float v3 = acc[i][3][r] + bj[3];
      float mx = fmaxf(fmaxf(v0, v1), fmaxf(v2, v3));
#pragma unroll
      for (int m = 1; m < 16; m <<= 1) mx = fmaxf(mx, __shfl_xor(mx, m));
      float sm = __expf(v0 - mx) + __expf(v1 - mx) + __expf(v2 - mx) + __expf(v3 - mx);
#pragma unroll
      for (int m = 1; m < 16; m <<= 1) sm += __shfl_xor(sm, m);
      if (lane15 == 0) {
        const int grow = rt * BMf + wr + i * 16 + q * 4 + r;
        pmax[(size_t)grow * NVT2 + pcol] = mx;
        psum[(size_t)grow * NVT2 + pcol] = sm;
      }
    }
  }
}

// ---------------- kernel 2: exact fp32 target logits
__global__ __launch_bounds__(256) void tgt_kernel(
    const float* __restrict__ inp, const float* __restrict__ W,
    const int* __restrict__ target, const float* __restrict__ bias,
    float* __restrict__ tl)
{
  const int row = blockIdx.x;
  int tgt = target[row];
  const int tgtc = tgt < 0 ? 0 : tgt;
  const float4* a = (const float4*)inp + (size_t)row * K4;
  const float4* w = (const float4*)W + (size_t)tgtc * K4;
  const int t = threadIdx.x;
  float s = 0.f;
  for (int i = t; i < K4; i += 256) {
    const float4 x = a[i], y = w[i];
    s += x.x * y.x + x.y * y.y + x.z * y.z + x.w * y.w;
  }
#pragma unroll
  for (int m = 1; m < 64; m <<= 1) s += __shfl_xor(s, m);
  __shared__ float red[4];
  if ((t & 63) == 0) red[t >> 6] = s;
  __syncthreads();
  if (t == 0) tl[row] = red[0] + red[1] + red[2] + red[3] + bias[tgtc];
}

// ---------------- kernel 3: merge partials -> tok_logp per row
__global__ __launch_bounds__(64) void lse_kernel(
    const float* __restrict__ pmax, const float* __restrict__ psum,
    const float* __restrict__ tl, float* __restrict__ tok)
{
  const int row = blockIdx.x;
  const int l = threadIdx.x;
  const float* pm = pmax + (size_t)row * NVT2;
  const float* ps = psum + (size_t)row * NVT2;
  float M = -3.4e38f;
  for (int t = l; t < NVT2; t += 64) M = fmaxf(M, pm[t]);
#pragma unroll
  for (int m = 1; m < 64; m <<= 1) M = fmaxf(M, __shfl_xor(M, m));
  float S = 0.f;
  for (int t = l; t < NVT2; t += 64) S += ps[t] * __expf(pm[t] - M);
#pragma unroll
  for (int m = 1; m < 64; m <<= 1) S += __shfl_xor(S, m);
  if (l == 0) tok[row] = tl[row] - (M + logf(S));
}

// ---------------- kernel 4: SimPO loss scalar
__global__ __launch_bounds__(512) void final_kernel(
    const float* __restrict__ tok, const int* __restrict__ target,
    float* __restrict__ out)
{
  const int w = threadIdx.x >> 6;
  const int l = threadIdx.x & 63;
  float s = 0.f, c = 0.f;
  for (int i = l; i < Tt; i += 64) {
    const int row = w * Tt + i;
    const bool msk = target[row] != -100;
    s += msk ? tok[row] : 0.f;
    c += msk ? 1.f : 0.f;
  }
#pragma unroll
  for (int m = 1; m < 64; m <<= 1) { s += __shfl_xor(s, m); c += __shfl_xor(c, m); }
  __shared__ float sums[8], cnts[8];
  if (l == 0) { sums[w] = s; cnts[w] = c; }
  __syncthreads();
  if (threadIdx.x == 0) {
    float avg[8];
    float nsum = 0.f, ncnt = 0.f;
    for (int b = 0; b < 8; ++b) {
      avg[b] = sums[b] / cnts[b];
      if (b < 4) { nsum += sums[b]; ncnt += cnts[b]; }
    }
    const float nll = -nsum / ncnt;
    float pref = 0.f;
    for (int i = 0; i < 4; ++i) {
      const float z = 0.1f * (avg[i] - avg[i + 4]) - 0.5f;
      const float ls = fminf(z, 0.f) - log1pf(__expf(-fabsf(z)));
      pref += -ls;                 // LABEL_SMOOTHING = 0
    }
    pref *= 0.25f;
    out[0] = 1.0f * nll + pref;    // ALPHA = 1
  }
}

extern "C" void kernel_launch(void* const* d_in, const int* in_sizes, int n_in,
                              void* d_out, int out_size, void* d_ws, size_t ws_size,
                              hipStream_t stream) {
  const float* W    = (const float*)d_in[0];
  const float* inp  = (const float*)d_in[1];
  const int*   tgt  = (const int*)d_in[2];
  const float* bias = (const float*)d_in[3];
  char* ws = (char*)d_ws;

  constexpr size_t szWb   = (size_t)Vv * Hh * 2;       // 131,072,000
  constexpr size_t szInb  = (size_t)Mrows * Hh * 2;    //  16,777,216
  constexpr size_t szPart = (size_t)Mrows * NVT2 * 4;  //   8,192,000
  constexpr size_t need   = szWb + szInb + 2 * szPart + 2 * (size_t)Mrows * 4;

  if (ws_size >= need) {
    ushort_t* Wb   = (ushort_t*)ws;
    ushort_t* inpb = (ushort_t*)(ws + szWb);
    float* pmax = (float*)(ws + szWb + szInb);
    float* psum = (float*)(ws + szWb + szInb + szPart);
    float* tl   = (float*)(ws + szWb + szInb + 2 * szPart);
    float* tok  = (float*)(ws + szWb + szInb + 2 * szPart + (size_t)Mrows * 4);

    hipLaunchKernelGGL(cvt_kernel, dim3(2048), dim3(256), 0, stream,
                       W, (unsigned*)Wb, Vv * Hh / 4);
    hipLaunchKernelGGL(cvt_kernel, dim3(2048), dim3(256), 0, stream,
                       inp, (unsigned*)inpb, Mrows * Hh / 4);
    hipLaunchKernelGGL(gemm256, dim3(2000), dim3(512), 131072, stream,
                       Wb, inpb, bias, pmax, psum);
    hipLaunchKernelGGL(tgt_kernel, dim3(Mrows), dim3(256), 0, stream,
                       inp, W, tgt, bias, tl);
    hipLaunchKernelGGL(lse_kernel, dim3(Mrows), dim3(64), 0, stream,
                       pmax, psum, tl, tok);
    hipLaunchKernelGGL(final_kernel, dim3(1), dim3(512), 0, stream,
                       tok, tgt, (float*)d_out);
  } else {
    float* pmax = (float*)ws;
    float* psum = (float*)(ws + szPart);
    float* tl   = (float*)(ws + 2 * szPart);
    float* tok  = (float*)(ws + 2 * szPart + (size_t)Mrows * 4);

    hipLaunchKernelGGL(gemm_partials, dim3(NRTf * NVTf), dim3(256), 0, stream,
                       W, inp, bias, pmax, psum);
    hipLaunchKernelGGL(tgt_kernel, dim3(Mrows), dim3(256), 0, stream,
                       inp, W, tgt, bias, tl);
    hipLaunchKernelGGL(lse_kernel, dim3(Mrows), dim3(64), 0, stream,
                       pmax, psum, tl, tok);
    hipLaunchKernelGGL(final_kernel, dim3(1), dim3(512), 0, stream,
                       tok, tgt, (float*)d_out);
  }
}